// Round 1
// baseline (450.374 us; speedup 1.0000x reference)
//
#include <hip/hip_runtime.h>

// Problem constants (reference: B=4096, CELL=400, K=10, T=256, V=80)
#define BB   4096
#define CELL 400
#define KK   10
#define TT   256
#define VV   80
// 3K = 30 params per row; block = 320 threads (5 waves)

__global__ __launch_bounds__(320) void window_kernel(
    const float* __restrict__ x,         // [B, CELL]
    const float* __restrict__ kappa_old, // [B, K]
    const float* __restrict__ onehots,   // [B, T, V]
    const float* __restrict__ W,         // [3K, CELL]
    const float* __restrict__ bias,      // [3K]
    float* __restrict__ out)             // [B*V weight][B*K kappa] concatenated
{
    __shared__ float  x_lds[CELL];
    __shared__ float  ko_lds[KK];
    __shared__ float  alpha_lds[KK], beta_lds[KK], kappa_lds[KK];
    __shared__ float  phi_lds[TT];
    __shared__ float4 part_lds[320];

    const int b   = blockIdx.x;
    const int tid = threadIdx.x;

    const float4* oh4 = (const float4*)(onehots + (size_t)b * TT * VV);

    // ---- Phase 1a: stage x row (+ kappa_old) into LDS ----
    if (tid < 100) {
        const float4* x4 = (const float4*)(x + (size_t)b * CELL);
        ((float4*)x_lds)[tid] = x4[tid];
    } else if (tid < 100 + KK) {
        ko_lds[tid - 100] = kappa_old[(size_t)b * KK + (tid - 100)];
    }
    // Register-prefetch the first 4 phase-4 iterations (20 KB/block).
    // Issued here so the HBM latency overlaps the phase-1b/3 prologue.
    const float4 pf0 = oh4[tid];
    const float4 pf1 = oh4[tid + 320];
    const float4 pf2 = oh4[tid + 640];
    const float4 pf3 = oh4[tid + 960];
    __syncthreads();

    // ---- Phase 1b: params = x @ W^T + b, fused exp + LDS/kappa write ----
    // (phase 2 of the previous version is folded into the r==0 tail:
    //  the owner thread of param j applies exp and writes alpha/beta/kappa
    //  directly — one barrier and one phase removed)
    if (tid < 240) {
        const int j = tid >> 3;        // output index 0..29
        const int r = tid & 7;         // lane-in-group
        const float* wrow = W + j * CELL + r * 50;
        const float* xs   = x_lds + r * 50;
        float s = 0.f;
        #pragma unroll
        for (int i = 0; i < 50; ++i) s += xs[i] * wrow[i];
        s += __shfl_down(s, 4, 8);
        s += __shfl_down(s, 2, 8);
        s += __shfl_down(s, 1, 8);
        if (r == 0) {
            const float e = __expf(s + bias[j]);
            if (j < KK) {
                alpha_lds[j] = e;
            } else if (j < 2 * KK) {
                beta_lds[j - KK] = e;
            } else {
                const float ka = ko_lds[j - 2 * KK] + e;
                kappa_lds[j - 2 * KK] = ka;
                out[(size_t)BB * VV + (size_t)b * KK + (j - 2 * KK)] = ka;
            }
        }
    }
    __syncthreads();

    // ---- Phase 3: phi[t] = sum_k alpha_k * exp(-beta_k * (kappa_k - t)^2) ----
    if (tid < TT) {
        const float u = (float)tid;
        float s = 0.f;
        #pragma unroll
        for (int k = 0; k < KK; ++k) {
            float d = kappa_lds[k] - u;
            s += alpha_lds[k] * __expf(-beta_lds[k] * d * d);
        }
        phi_lds[tid] = s;
    }
    __syncthreads();

    // ---- Phase 4: weight[v] = sum_t phi[t] * onehots[b,t,v] ----
    // Row is 256*80 floats = 5120 float4. tid = g*20+vv; flat float4 index
    // tid + 320*it is fully contiguous per iteration (perfect coalescing).
    {
        const int g = tid / 20;  // 0..15
        float4 acc = {0.f, 0.f, 0.f, 0.f};
        // first 4 iterations come from the prefetch registers
        {
            const float ph = phi_lds[g];
            acc.x += ph * pf0.x; acc.y += ph * pf0.y;
            acc.z += ph * pf0.z; acc.w += ph * pf0.w;
        }
        {
            const float ph = phi_lds[g + 16];
            acc.x += ph * pf1.x; acc.y += ph * pf1.y;
            acc.z += ph * pf1.z; acc.w += ph * pf1.w;
        }
        {
            const float ph = phi_lds[g + 32];
            acc.x += ph * pf2.x; acc.y += ph * pf2.y;
            acc.z += ph * pf2.z; acc.w += ph * pf2.w;
        }
        {
            const float ph = phi_lds[g + 48];
            acc.x += ph * pf3.x; acc.y += ph * pf3.y;
            acc.z += ph * pf3.z; acc.w += ph * pf3.w;
        }
        #pragma unroll
        for (int it = 4; it < 16; ++it) {
            const float ph = phi_lds[g + 16 * it];
            const float4 o = oh4[tid + 320 * it];
            acc.x += ph * o.x;
            acc.y += ph * o.y;
            acc.z += ph * o.z;
            acc.w += ph * o.w;
        }
        part_lds[tid] = acc;
    }
    __syncthreads();

    // ---- Phase 5: reduce 16 partials per v-float4, store weight ----
    if (tid < 20) {
        float4 s = {0.f, 0.f, 0.f, 0.f};
        #pragma unroll
        for (int g = 0; g < 16; ++g) {
            const float4 p = part_lds[g * 20 + tid];
            s.x += p.x; s.y += p.y; s.z += p.z; s.w += p.w;
        }
        float4* o4 = (float4*)(out + (size_t)b * VV);
        o4[tid] = s;
    }
}

extern "C" void kernel_launch(void* const* d_in, const int* in_sizes, int n_in,
                              void* d_out, int out_size, void* d_ws, size_t ws_size,
                              hipStream_t stream) {
    const float* x         = (const float*)d_in[0];
    const float* kappa_old = (const float*)d_in[1];
    const float* onehots   = (const float*)d_in[2];
    const float* W         = (const float*)d_in[3];
    const float* bias      = (const float*)d_in[4];
    // d_in[5] = text_len (=256), compile-time constant here
    float* out = (float*)d_out;

    window_kernel<<<BB, 320, 0, stream>>>(x, kappa_old, onehots, W, bias, out);
}